// Round 1
// baseline (510.292 us; speedup 1.0000x reference)
//
#include <hip/hip_runtime.h>

// LocallyConnected2d: y[b,o,h,w] = bias[o,h,w] +
//   sum_{i,kh,kw} xpad[b,i,h+kh,w+kw] * weight[i,o,h,w,kh,kw]
// B=64, CIN=COUT=64, H=W=HOUT=WOUT=32, K=3, pad=1, fp32.

#define B_      64
#define CIN_    64
#define COUT_   64
#define HW_     32
#define HP_     34                       // padded spatial extent
#define NLOC    (HW_*HW_)                // 1024
#define W_IST   (COUT_*NLOC*9)           // 589824 floats per cin
#define W_OST   (NLOC*9)                 // 9216 floats per cout
#define XT_FLOATS ((size_t)CIN_*HP_*HP_*B_)   // 4,734,976 floats = 18.9 MB

// ---------------------------------------------------------------------------
// Kernel 1: transpose+pad  x[b][i][h][w] -> xt[i][hh][ww][b], zero borders.
// Reads coalesced along w, writes coalesced along b (b innermost).
// ---------------------------------------------------------------------------
__global__ __launch_bounds__(256) void xpose_pad(const float* __restrict__ x,
                                                 float* __restrict__ xt) {
  int bid = blockIdx.x;                  // CIN_*HP_ = 2176 blocks
  int i   = bid / HP_;
  int hh  = bid % HP_;
  __shared__ float tile[B_ * 33];        // [b][w], stride 33 -> conflict-free
  int t = threadIdx.x;
  bool interior = (hh >= 1 && hh <= HW_);
  if (interior) {
    int h = hh - 1;
    int w = t & 31, bs = t >> 5;
    #pragma unroll
    for (int r = 0; r < 8; ++r) {
      int b = r * 8 + bs;
      tile[b * 33 + w] = x[(((size_t)b * CIN_ + i) * HW_ + h) * HW_ + w];
    }
  }
  __syncthreads();
  int b = t & 63, wsb = t >> 6;
  size_t base = (((size_t)i * HP_ + hh) * HP_) * B_;
  #pragma unroll
  for (int s = 0; s < 9; ++s) {
    int ww = s * 4 + wsb;
    if (ww < HP_) {
      float v = 0.f;
      if (interior && ww >= 1 && ww <= HW_) v = tile[b * 33 + (ww - 1)];
      xt[base + (size_t)ww * B_ + b] = v;   // contiguous 1KB per round
    }
  }
}

// ---------------------------------------------------------------------------
// Kernel 2: one block per output location (h,w). 256 threads = 4 waves.
// lanes <-> batch b (so weight addresses are wave-uniform -> scalar pipe),
// wave  <-> 16-cout group. Each thread: 16 accumulators.
// A (im2col column for this loc) staged in LDS per 8-cin chunk.
// XT=true reads the padded transposed x (coalesced); XT=false is the
// d_ws-too-small fallback reading x directly (correct, uncoalesced).
// ---------------------------------------------------------------------------
template <bool XT>
__global__ __launch_bounds__(256, 4) void lc2d(const float* __restrict__ xsrc,
                                               const float* __restrict__ weight,
                                               const float* __restrict__ bias,
                                               float* __restrict__ out) {
  int t0  = blockIdx.x;
  // XCD swizzle: each XCD gets 128 consecutive locs (4 full h-rows) so the
  // 4B-scattered output stores of neighboring-w blocks merge in one L2.
  int loc = ((t0 & 7) << 7) | (t0 >> 3);
  int h = loc >> 5, w = loc & 31;
  int tid = threadIdx.x;
  int b   = tid & 63;
  int o0  = __builtin_amdgcn_readfirstlane(tid >> 6) * 16;

  __shared__ float As[72 * 64];          // [k = kk*8+isub][b]  18.4 KB

  float acc[16];
  #pragma unroll
  for (int j = 0; j < 16; ++j) acc[j] = bias[(size_t)(o0 + j) * NLOC + loc];

  for (int ic = 0; ic < 8; ++ic) {       // 8 chunks of 8 cin
    __syncthreads();
    // stage 72x64 floats; k = kk*8 + isub so decode is pure shifts
    #pragma unroll
    for (int s = 0; s < 18; ++s) {
      int f  = s * 256 + tid;
      int k  = f >> 6;                   // 0..71
      int lb = f & 63;
      int kk = k >> 3, isub = k & 7;
      int i  = ic * 8 + isub;
      int kh = kk / 3, kw = kk - kh * 3;
      float v;
      if (XT) {
        v = xsrc[(((size_t)i * HP_ + (h + kh)) * HP_ + (w + kw)) * B_ + lb];
      } else {
        int hh = h + kh - 1, ww = w + kw - 1;
        v = (hh >= 0 && hh < HW_ && ww >= 0 && ww < HW_)
              ? xsrc[(((size_t)lb * CIN_ + i) * HW_ + hh) * HW_ + ww]
              : 0.f;
      }
      As[k * 64 + lb] = v;
    }
    __syncthreads();

    #pragma unroll 1
    for (int isub = 0; isub < 8; ++isub) {
      const float* wp = weight + (size_t)(ic * 8 + isub) * W_IST
                               + (size_t)o0 * W_OST + loc * 9;
      #pragma unroll
      for (int kk = 0; kk < 9; ++kk) {
        float a = As[(kk * 8 + isub) * 64 + b];   // 1 ds_read, reused 16x
        #pragma unroll
        for (int j = 0; j < 16; ++j)
          acc[j] = fmaf(a, wp[(size_t)j * W_OST + kk], acc[j]);
      }
    }
  }

  size_t ob = ((size_t)b * COUT_ + o0) * NLOC + loc;
  #pragma unroll
  for (int j = 0; j < 16; ++j) out[ob + (size_t)j * NLOC] = acc[j];
}

// ---------------------------------------------------------------------------
extern "C" void kernel_launch(void* const* d_in, const int* in_sizes, int n_in,
                              void* d_out, int out_size, void* d_ws, size_t ws_size,
                              hipStream_t stream) {
  const float* x  = (const float*)d_in[0];
  const float* wt = (const float*)d_in[1];
  const float* bs = (const float*)d_in[2];
  float* out = (float*)d_out;

  if (ws_size >= XT_FLOATS * sizeof(float)) {
    float* xt = (float*)d_ws;
    xpose_pad<<<CIN_ * HP_, 256, 0, stream>>>(x, xt);
    lc2d<true><<<NLOC, 256, 0, stream>>>(xt, wt, bs, out);
  } else {
    lc2d<false><<<NLOC, 256, 0, stream>>>(x, wt, bs, out);
  }
}

// Round 2
// 335.032 us; speedup vs baseline: 1.5231x; 1.5231x over previous
//
#include <hip/hip_runtime.h>
#include <hip/hip_bf16.h>

// LocallyConnected2d: y[b,o,h,w] = bias[o,h,w] +
//   sum_{i,kh,kw} xpad[b,i,h+kh,w+kw] * weight[i,o,h,w,kh,kw]
// B=64, CIN=COUT=64, H=W=32, K=3, pad=1, fp32 in/out.
// Strategy: per-loc GEMM Y[64b][64o] += X[64b][576k] W[576k][64o] on bf16 MFMA.

#define B_    64
#define HW_   32
#define HP_   34
#define NLOC  1024
#define W_OST 9216u     // floats per o step
#define W_IST 589824u   // floats per i step
#define XT_BYTES ((size_t)64*HP_*HP_*64*2)   // 9,469,952

typedef __attribute__((ext_vector_type(8))) short short8;
typedef __attribute__((ext_vector_type(8))) unsigned short ushort8;
typedef __attribute__((ext_vector_type(4))) float floatx4;

static __device__ __forceinline__ unsigned short f2bf(float f) {
  __hip_bfloat16 h = __float2bfloat16(f);   // RNE
  return __builtin_bit_cast(unsigned short, h);
}

// ---------------------------------------------------------------------------
// Kernel 1: pad+transpose x[b][i][h][w] (fp32) -> xt[i][hh][ww][b] (bf16).
// ---------------------------------------------------------------------------
__global__ __launch_bounds__(256) void xpose_pad(const float* __restrict__ x,
                                                 unsigned short* __restrict__ xt) {
  int bid = blockIdx.x;                 // 64*34
  int i = bid / HP_, hh = bid % HP_;
  __shared__ float tile[B_ * 33];
  int t = threadIdx.x;
  bool interior = (hh >= 1 && hh <= HW_);
  if (interior) {
    int h = hh - 1, w = t & 31, bs = t >> 5;
    #pragma unroll
    for (int r = 0; r < 8; ++r) {
      int b = r * 8 + bs;
      tile[b * 33 + w] = x[(((size_t)b * 64 + i) * HW_ + h) * HW_ + w];
    }
  }
  __syncthreads();
  int b = t & 63, wsb = t >> 6;
  size_t base = (size_t)(i * HP_ + hh) * HP_ * B_;
  #pragma unroll
  for (int s = 0; s < 9; ++s) {
    int ww = s * 4 + wsb;
    if (ww < HP_) {
      float v = 0.f;
      if (interior && ww >= 1 && ww <= HW_) v = tile[b * 33 + (ww - 1)];
      xt[base + (size_t)ww * B_ + b] = f2bf(v);
    }
  }
}

// ---------------------------------------------------------------------------
// Kernel 2: one block per loc. 4 waves = 4 o-tiles of 16. K=576 in 18 chunks
// of 32 (k = i*9 + kh*3 + kw). A staged to LDS in MFMA-fragment order
// (per-wave 2-step transpose, conflict-free); W gathered global->VGPR per
// lane (one 36-B granule run per (o,chunk)), cvt bf16, depth-1 prefetch.
// ---------------------------------------------------------------------------
__global__ __launch_bounds__(256, 4) void lc2d_mfma(
    const unsigned short* __restrict__ xt,
    const float* __restrict__ weight,
    const float* __restrict__ bias,
    float* __restrict__ out) {
  __shared__ unsigned short As[9 * 4 * 64 * 8];   // 36 KB: [cc][tile][lane][8j]
  __shared__ unsigned short scr[4][512];          // 1 KB per-wave transpose scratch

  const int bid  = blockIdx.x;
  const int loc  = ((bid & 7) << 7) | (bid >> 3);   // XCD swizzle: 4 h-rows/XCD
  const int hblk = loc >> 5, wblk = loc & 31;
  const int tid  = threadIdx.x;
  const int lane = tid & 63;
  const int wv   = tid >> 6;            // wave id = o-tile
  const int h4   = lane >> 4;           // k-quad of the MFMA fragments
  const int oo   = (wv << 4) + (lane & 15);

  const unsigned wbase = (unsigned)oo * W_OST + (unsigned)loc * 9u;

  floatx4 acc[4];
  {
    float bv = bias[(unsigned)oo * 1024u + (unsigned)loc];
    floatx4 z = {bv, bv, bv, bv};
    acc[0] = z; acc[1] = z; acc[2] = z; acc[3] = z;
  }

  float wreg[2][8];

  // ---- per-lane weight gather for chunk c: k = 32c + 8*h4 + j, (i,kk)=divmod(k,9)
  auto loadW = [&](int c, float* d) {
    unsigned kb  = (unsigned)(c * 32) + (unsigned)(h4 * 8);
    unsigned i0  = kb / 9u;
    unsigned kk0 = kb - i0 * 9u;
    unsigned off0 = i0 * W_IST + wbase + kk0;
    #pragma unroll
    for (int j = 0; j < 8; ++j) {
      unsigned off = off0 + (unsigned)j + ((kk0 + (unsigned)j >= 9u) ? (W_IST - 9u) : 0u);
      d[j] = weight[off];
    }
  };

  auto packW = [&](const float* s) {
    short8 r;
    #pragma unroll
    for (int j = 0; j < 8; ++j) r[j] = (short)f2bf(s[j]);
    return r;
  };

  // ---- stage half hf: each wave stages the h-quad == wv slots of 9 chunks
  auto stage = [&](int hf) {
    #pragma unroll
    for (int r = 0; r < 9; ++r) {
      const int c = hf * 9 + r;
      // step 1: coalesced load of 8 k-rows x 64 b (1 KB) into wave scratch
      int k  = c * 32 + wv * 8 + (lane >> 3);
      int i  = k / 9, q = k - i * 9;
      int kh = q / 3, kw = q - kh * 3;
      const ushort8* src = (const ushort8*)(xt +
          (((unsigned)i * HP_ + (unsigned)(hblk + kh)) * HP_ + (unsigned)(wblk + kw)) * 64u
          + ((unsigned)(lane & 7) << 3));
      ushort8 v = *src;
      *(ushort8*)&scr[wv][lane << 3] = v;   // [jr=lane>>3][b=8*(lane&7)+e]
      __asm__ volatile("s_waitcnt lgkmcnt(0)" ::: "memory");
      // step 2: lane-transpose: lane packs b=lane's 8 j-values -> one frag slot
      ushort8 p;
      #pragma unroll
      for (int jr = 0; jr < 8; ++jr) p[jr] = scr[wv][jr * 64 + lane];
      unsigned slot = (unsigned)(r * 4 + (lane >> 4)) * 64u + (unsigned)(lane & 15) + (unsigned)(wv << 4);
      *(ushort8*)&As[slot << 3] = p;
      __asm__ volatile("s_waitcnt lgkmcnt(0)" ::: "memory");  // reads done before next overwrite
    }
  };

  loadW(0, wreg[0]);
  stage(0);
  __syncthreads();

  #pragma unroll
  for (int c = 0; c < 9; ++c) {
    loadW(c + 1, wreg[(c + 1) & 1]);          // prefetch (c=8 prefetches chunk 9)
    short8 bw = packW(wreg[c & 1]);
    #pragma unroll
    for (int tl = 0; tl < 4; ++tl) {
      const short8 av = *(const short8*)&As[((unsigned)(c * 4 + tl) * 64u + (unsigned)lane) << 3];
      acc[tl] = __builtin_amdgcn_mfma_f32_16x16x32_bf16(av, bw, acc[tl], 0, 0, 0);
    }
  }

  __syncthreads();
  stage(1);
  __syncthreads();

  #pragma unroll
  for (int c = 9; c < 18; ++c) {
    if (c < 17) loadW(c + 1, wreg[(c + 1) & 1]);
    short8 bw = packW(wreg[c & 1]);
    #pragma unroll
    for (int tl = 0; tl < 4; ++tl) {
      const short8 av = *(const short8*)&As[((unsigned)((c - 9) * 4 + tl) * 64u + (unsigned)lane) << 3];
      acc[tl] = __builtin_amdgcn_mfma_f32_16x16x32_bf16(av, bw, acc[tl], 0, 0, 0);
    }
  }

  // epilogue: D lane mapping col=o=lane&15, row=b=tile*16 + h4*4 + r
  #pragma unroll
  for (int tl = 0; tl < 4; ++tl) {
    int brow = tl * 16 + h4 * 4;
    #pragma unroll
    for (int r = 0; r < 4; ++r)
      out[((unsigned)(brow + r) * 64u + (unsigned)oo) * 1024u + (unsigned)loc] = acc[tl][r];
  }
}

// ---------------------------------------------------------------------------
// Fallback (ws too small): correct fp32 path from round 1 (direct x reads).
// ---------------------------------------------------------------------------
__global__ __launch_bounds__(256, 4) void lc2d_fallback(
    const float* __restrict__ x, const float* __restrict__ weight,
    const float* __restrict__ bias, float* __restrict__ out) {
  int t0 = blockIdx.x;
  int loc = ((t0 & 7) << 7) | (t0 >> 3);
  int h = loc >> 5, w = loc & 31;
  int tid = threadIdx.x;
  int b = tid & 63;
  int o0 = (tid >> 6) * 16;
  __shared__ float As[72 * 64];
  float acc[16];
  #pragma unroll
  for (int j = 0; j < 16; ++j) acc[j] = bias[(size_t)(o0 + j) * NLOC + loc];
  for (int ic = 0; ic < 8; ++ic) {
    __syncthreads();
    #pragma unroll
    for (int s = 0; s < 18; ++s) {
      int f = s * 256 + tid;
      int k = f >> 6, lb = f & 63;
      int kk = k >> 3, isub = k & 7;
      int i = ic * 8 + isub;
      int kh = kk / 3, kw = kk - kh * 3;
      int hh = h + kh - 1, ww = w + kw - 1;
      float v = (hh >= 0 && hh < HW_ && ww >= 0 && ww < HW_)
                  ? x[(((size_t)lb * 64 + i) * HW_ + hh) * HW_ + ww] : 0.f;
      As[k * 64 + lb] = v;
    }
    __syncthreads();
    #pragma unroll 1
    for (int isub = 0; isub < 8; ++isub) {
      const float* wp = weight + (size_t)(ic * 8 + isub) * W_IST
                               + (size_t)o0 * W_OST + loc * 9;
      #pragma unroll
      for (int kk = 0; kk < 9; ++kk) {
        float a = As[(kk * 8 + isub) * 64 + b];
        #pragma unroll
        for (int j = 0; j < 16; ++j)
          acc[j] = fmaf(a, wp[(size_t)j * W_OST + kk], acc[j]);
      }
    }
  }
  size_t ob = ((size_t)b * 64 + o0) * NLOC + loc;
  #pragma unroll
  for (int j = 0; j < 16; ++j) out[ob + (size_t)j * NLOC] = acc[j];
}

// ---------------------------------------------------------------------------
extern "C" void kernel_launch(void* const* d_in, const int* in_sizes, int n_in,
                              void* d_out, int out_size, void* d_ws, size_t ws_size,
                              hipStream_t stream) {
  const float* x  = (const float*)d_in[0];
  const float* wt = (const float*)d_in[1];
  const float* bs = (const float*)d_in[2];
  float* out = (float*)d_out;

  if (ws_size >= XT_BYTES) {
    unsigned short* xtb = (unsigned short*)d_ws;
    xpose_pad<<<64 * HP_, 256, 0, stream>>>(x, xtb);
    lc2d_mfma<<<NLOC, 256, 0, stream>>>(xtb, wt, bs, out);
  } else {
    lc2d_fallback<<<NLOC, 256, 0, stream>>>(x, wt, bs, out);
  }
}

// Round 3
// 290.288 us; speedup vs baseline: 1.7579x; 1.1541x over previous
//
#include <hip/hip_runtime.h>
#include <hip/hip_bf16.h>

// LocallyConnected2d: y[b,o,h,w] = bias[o,h,w] +
//   sum_{i,kh,kw} xpad[b,i,h+kh,w+kw] * weight[i,o,h,w,kh,kw]
// B=64, CIN=COUT=64, H=W=32, K=3, pad=1, fp32 in/out.
// Per-loc GEMM Y[64b][64o] += X[64b][576k] W[576k][64o] on bf16 MFMA.
// Round 3: pre-format weight into MFMA B-fragment order (coalesced both ways)
// so the main kernel's weight feed is dwordx4-dense instead of 4B scatter.

#define B_    64
#define HW_   32
#define HP_   34
#define NLOC  1024
#define W_OST 9216u     // floats per o step
#define W_IST 589824u   // floats per i step
#define XT_BYTES  ((size_t)64*HP_*HP_*64*2)          // 9,469,952
#define WT2_BYTES ((size_t)NLOC*18*4*64*16)          // 75,497,472
#define WS_NEED   (XT_BYTES + WT2_BYTES)             // 84,967,424

typedef __attribute__((ext_vector_type(8))) short short8;
typedef __attribute__((ext_vector_type(8))) unsigned short ushort8;
typedef __attribute__((ext_vector_type(4))) float floatx4;

static __device__ __forceinline__ unsigned short f2bf(float f) {
  __hip_bfloat16 h = __float2bfloat16(f);   // RNE
  return __builtin_bit_cast(unsigned short, h);
}

// ---------------------------------------------------------------------------
// Kernel 1: pad+transpose x[b][i][h][w] (fp32) -> xt[i][hh][ww][b] (bf16).
// ---------------------------------------------------------------------------
__global__ __launch_bounds__(256) void xpose_pad(const float* __restrict__ x,
                                                 unsigned short* __restrict__ xt) {
  int bid = blockIdx.x;                 // 64*34
  int i = bid / HP_, hh = bid % HP_;
  __shared__ float tile[B_ * 33];
  int t = threadIdx.x;
  bool interior = (hh >= 1 && hh <= HW_);
  if (interior) {
    int h = hh - 1, w = t & 31, bs = t >> 5;
    #pragma unroll
    for (int r = 0; r < 8; ++r) {
      int b = r * 8 + bs;
      tile[b * 33 + w] = x[(((size_t)b * 64 + i) * HW_ + h) * HW_ + w];
    }
  }
  __syncthreads();
  int b = t & 63, wsb = t >> 6;
  size_t base = (size_t)(i * HP_ + hh) * HP_ * B_;
  #pragma unroll
  for (int s = 0; s < 9; ++s) {
    int ww = s * 4 + wsb;
    if (ww < HP_) {
      float v = 0.f;
      if (interior && ww >= 1 && ww <= HW_) v = tile[b * 33 + (ww - 1)];
      xt[base + (size_t)ww * B_ + b] = f2bf(v);
    }
  }
}

// ---------------------------------------------------------------------------
// Kernel 2: weight -> wt2 in MFMA B-fragment order, bf16.
// wt2 slab (loc,c,tile): 64 lanes x 16B; lane holds W[k=c*32+(lane>>4)*8+j]
// [o=tile*16+(lane&15)], j=0..7.  Block = o-tile x 2 locs x all i.
// Reads coalesced along (loc,kk); writes coalesced along lane.
// ---------------------------------------------------------------------------
__global__ __launch_bounds__(256) void wtrans(const float* __restrict__ wsrc,
                                              unsigned short* __restrict__ wt2) {
  __shared__ unsigned short lds[16 * 2 * 584];   // [o16][loc2][k576 pad->584]
  int bid  = blockIdx.x;                         // 4 * 512
  int tile = bid & 3;
  int lblk = bid >> 2;
  int o0 = tile * 16, loc0 = lblk * 2;
  int t = threadIdx.x;

  // stage-in: 64i x 16o x (2loc*9kk=18) floats, float2 per thread per step
  #pragma unroll 4
  for (int s = 0; s < 36; ++s) {
    int f = (s * 256 + t) * 2;
    int i = f / 288;
    int rem = f - i * 288;
    int o = rem / 18;
    int q = rem - o * 18;                        // 0..17, even
    const float2 v = *(const float2*)(wsrc + (size_t)i * W_IST
                                      + (size_t)(o0 + o) * W_OST
                                      + (size_t)loc0 * 9 + q);
    int lc0 = q / 9, kk0 = q - lc0 * 9;
    lds[(o * 2 + lc0) * 584 + i * 9 + kk0] = f2bf(v.x);
    int q1 = q + 1, lc1 = q1 / 9, kk1 = q1 - lc1 * 9;
    lds[(o * 2 + lc1) * 584 + i * 9 + kk1] = f2bf(v.y);
  }
  __syncthreads();

  // stage-out: 36 slabs (2 loc x 18 c), 9 per wave, 1KB dense stores
  int lane = t & 63, wv = t >> 6;
  int on = lane & 15, quad = lane >> 4;
  #pragma unroll
  for (int r = 0; r < 9; ++r) {
    int sid = wv * 9 + r;
    int lc = sid / 18, c = sid - lc * 18;
    int k0 = c * 32 + quad * 8;
    ushort8 v = *(const ushort8*)&lds[(on * 2 + lc) * 584 + k0];
    *(ushort8*)(wt2 + ((((size_t)(loc0 + lc) * 18 + c) * 4 + tile) * 64 + lane) * 8) = v;
  }
}

// ---------------------------------------------------------------------------
// Kernel 3: main GEMM. One block per loc, 4 waves = 4 o-tiles.
// B-frags: direct dwordx4 from wt2 (depth-1 prefetch). A staged to LDS in
// fragment order via per-wave 2-step transpose (verified round 2).
// ---------------------------------------------------------------------------
__global__ __launch_bounds__(256, 4) void lc2d_mfma_pre(
    const unsigned short* __restrict__ xt,
    const unsigned short* __restrict__ wt2,
    const float* __restrict__ bias,
    float* __restrict__ out) {
  __shared__ unsigned short As[9 * 4 * 64 * 8];   // 36 KB [cc][tile][lane][8j]
  __shared__ unsigned short scr[4][512];

  const int bid  = blockIdx.x;
  const int loc  = ((bid & 7) << 7) | (bid >> 3);   // XCD swizzle
  const int hblk = loc >> 5, wblk = loc & 31;
  const int tid  = threadIdx.x;
  const int lane = tid & 63;
  const int wv   = tid >> 6;
  const int h4   = lane >> 4;
  const int oo   = (wv << 4) + (lane & 15);

  floatx4 acc[4];
  {
    float bv = bias[(unsigned)oo * 1024u + (unsigned)loc];
    floatx4 z = {bv, bv, bv, bv};
    acc[0] = z; acc[1] = z; acc[2] = z; acc[3] = z;
  }

  ushort8 breg[2];
  auto loadB = [&](int c, int slot) {
    breg[slot] = *(const ushort8*)(wt2 +
        ((((size_t)loc * 18 + c) * 4 + wv) * 64 + lane) * 8);
  };

  auto stage = [&](int hf) {
    #pragma unroll
    for (int r = 0; r < 9; ++r) {
      const int c = hf * 9 + r;
      int k  = c * 32 + wv * 8 + (lane >> 3);
      int i  = k / 9, q = k - i * 9;
      int kh = q / 3, kw = q - kh * 3;
      const ushort8* src = (const ushort8*)(xt +
          (((unsigned)i * HP_ + (unsigned)(hblk + kh)) * HP_ + (unsigned)(wblk + kw)) * 64u
          + ((unsigned)(lane & 7) << 3));
      ushort8 v = *src;
      *(ushort8*)&scr[wv][lane << 3] = v;
      __asm__ volatile("s_waitcnt lgkmcnt(0)" ::: "memory");
      ushort8 p;
      #pragma unroll
      for (int jr = 0; jr < 8; ++jr) p[jr] = scr[wv][jr * 64 + lane];
      unsigned slot = (unsigned)(r * 4 + (lane >> 4)) * 64u + (unsigned)(lane & 15) + (unsigned)(wv << 4);
      *(ushort8*)&As[slot << 3] = p;
      __asm__ volatile("s_waitcnt lgkmcnt(0)" ::: "memory");
    }
  };

  loadB(0, 0);
  stage(0);
  __syncthreads();

  #pragma unroll
  for (int c = 0; c < 9; ++c) {
    loadB(c + 1, (c + 1) & 1);
    short8 bw = __builtin_bit_cast(short8, breg[c & 1]);
    #pragma unroll
    for (int tl = 0; tl < 4; ++tl) {
      const short8 av = *(const short8*)&As[((unsigned)(c * 4 + tl) * 64u + (unsigned)lane) << 3];
      acc[tl] = __builtin_amdgcn_mfma_f32_16x16x32_bf16(av, bw, acc[tl], 0, 0, 0);
    }
  }

  __syncthreads();
  stage(1);
  __syncthreads();

  #pragma unroll
  for (int c = 9; c < 18; ++c) {
    if (c < 17) loadB(c + 1, (c + 1) & 1);
    short8 bw = __builtin_bit_cast(short8, breg[c & 1]);
    #pragma unroll
    for (int tl = 0; tl < 4; ++tl) {
      const short8 av = *(const short8*)&As[((unsigned)((c - 9) * 4 + tl) * 64u + (unsigned)lane) << 3];
      acc[tl] = __builtin_amdgcn_mfma_f32_16x16x32_bf16(av, bw, acc[tl], 0, 0, 0);
    }
  }

  #pragma unroll
  for (int tl = 0; tl < 4; ++tl) {
    int brow = tl * 16 + h4 * 4;
    #pragma unroll
    for (int r = 0; r < 4; ++r)
      out[((unsigned)(brow + r) * 64u + (unsigned)oo) * 1024u + (unsigned)loc] = acc[tl][r];
  }
}

// ---------------------------------------------------------------------------
// Mid fallback (ws >= XT only): round-2 kernel — per-lane weight gather.
// ---------------------------------------------------------------------------
__global__ __launch_bounds__(256, 4) void lc2d_mfma_gather(
    const unsigned short* __restrict__ xt,
    const float* __restrict__ weight,
    const float* __restrict__ bias,
    float* __restrict__ out) {
  __shared__ unsigned short As[9 * 4 * 64 * 8];
  __shared__ unsigned short scr[4][512];

  const int bid  = blockIdx.x;
  const int loc  = ((bid & 7) << 7) | (bid >> 3);
  const int hblk = loc >> 5, wblk = loc & 31;
  const int tid  = threadIdx.x;
  const int lane = tid & 63;
  const int wv   = tid >> 6;
  const int h4   = lane >> 4;
  const int oo   = (wv << 4) + (lane & 15);
  const unsigned wbase = (unsigned)oo * W_OST + (unsigned)loc * 9u;

  floatx4 acc[4];
  {
    float bv = bias[(unsigned)oo * 1024u + (unsigned)loc];
    floatx4 z = {bv, bv, bv, bv};
    acc[0] = z; acc[1] = z; acc[2] = z; acc[3] = z;
  }
  float wreg[2][8];
  auto loadW = [&](int c, float* d) {
    unsigned kb = (unsigned)(c * 32) + (unsigned)(h4 * 8);
    unsigned i0 = kb / 9u, kk0 = kb - i0 * 9u;
    unsigned off0 = i0 * W_IST + wbase + kk0;
    #pragma unroll
    for (int j = 0; j < 8; ++j) {
      unsigned off = off0 + (unsigned)j + ((kk0 + (unsigned)j >= 9u) ? (W_IST - 9u) : 0u);
      d[j] = weight[off];
    }
  };
  auto packW = [&](const float* s) {
    short8 r;
    #pragma unroll
    for (int j = 0; j < 8; ++j) r[j] = (short)f2bf(s[j]);
    return r;
  };
  auto stage = [&](int hf) {
    #pragma unroll
    for (int r = 0; r < 9; ++r) {
      const int c = hf * 9 + r;
      int k = c * 32 + wv * 8 + (lane >> 3);
      int i = k / 9, q = k - i * 9;
      int kh = q / 3, kw = q - kh * 3;
      const ushort8* src = (const ushort8*)(xt +
          (((unsigned)i * HP_ + (unsigned)(hblk + kh)) * HP_ + (unsigned)(wblk + kw)) * 64u
          + ((unsigned)(lane & 7) << 3));
      ushort8 v = *src;
      *(ushort8*)&scr[wv][lane << 3] = v;
      __asm__ volatile("s_waitcnt lgkmcnt(0)" ::: "memory");
      ushort8 p;
      #pragma unroll
      for (int jr = 0; jr < 8; ++jr) p[jr] = scr[wv][jr * 64 + lane];
      unsigned slot = (unsigned)(r * 4 + (lane >> 4)) * 64u + (unsigned)(lane & 15) + (unsigned)(wv << 4);
      *(ushort8*)&As[slot << 3] = p;
      __asm__ volatile("s_waitcnt lgkmcnt(0)" ::: "memory");
    }
  };

  loadW(0, wreg[0]);
  stage(0);
  __syncthreads();
  #pragma unroll
  for (int c = 0; c < 9; ++c) {
    loadW(c + 1, wreg[(c + 1) & 1]);
    short8 bw = packW(wreg[c & 1]);
    #pragma unroll
    for (int tl = 0; tl < 4; ++tl) {
      const short8 av = *(const short8*)&As[((unsigned)(c * 4 + tl) * 64u + (unsigned)lane) << 3];
      acc[tl] = __builtin_amdgcn_mfma_f32_16x16x32_bf16(av, bw, acc[tl], 0, 0, 0);
    }
  }
  __syncthreads();
  stage(1);
  __syncthreads();
  #pragma unroll
  for (int c = 9; c < 18; ++c) {
    if (c < 17) loadW(c + 1, wreg[(c + 1) & 1]);
    short8 bw = packW(wreg[c & 1]);
    #pragma unroll
    for (int tl = 0; tl < 4; ++tl) {
      const short8 av = *(const short8*)&As[((unsigned)((c - 9) * 4 + tl) * 64u + (unsigned)lane) << 3];
      acc[tl] = __builtin_amdgcn_mfma_f32_16x16x32_bf16(av, bw, acc[tl], 0, 0, 0);
    }
  }
  #pragma unroll
  for (int tl = 0; tl < 4; ++tl) {
    int brow = tl * 16 + h4 * 4;
    #pragma unroll
    for (int r = 0; r < 4; ++r)
      out[((unsigned)(brow + r) * 64u + (unsigned)oo) * 1024u + (unsigned)loc] = acc[tl][r];
  }
}

// ---------------------------------------------------------------------------
// Last fallback: fp32, direct x reads (round 1, correct).
// ---------------------------------------------------------------------------
__global__ __launch_bounds__(256, 4) void lc2d_fallback(
    const float* __restrict__ x, const float* __restrict__ weight,
    const float* __restrict__ bias, float* __restrict__ out) {
  int t0 = blockIdx.x;
  int loc = ((t0 & 7) << 7) | (t0 >> 3);
  int h = loc >> 5, w = loc & 31;
  int tid = threadIdx.x;
  int b = tid & 63;
  int o0 = (tid >> 6) * 16;
  __shared__ float As[72 * 64];
  float acc[16];
  #pragma unroll
  for (int j = 0; j < 16; ++j) acc[j] = bias[(size_t)(o0 + j) * NLOC + loc];
  for (int ic = 0; ic < 8; ++ic) {
    __syncthreads();
    #pragma unroll
    for (int s = 0; s < 18; ++s) {
      int f = s * 256 + tid;
      int k = f >> 6, lb = f & 63;
      int kk = k >> 3, isub = k & 7;
      int i = ic * 8 + isub;
      int kh = kk / 3, kw = kk - kh * 3;
      int hh = h + kh - 1, ww = w + kw - 1;
      float v = (hh >= 0 && hh < HW_ && ww >= 0 && ww < HW_)
                  ? x[(((size_t)lb * 64 + i) * HW_ + hh) * HW_ + ww] : 0.f;
      As[k * 64 + lb] = v;
    }
    __syncthreads();
    #pragma unroll 1
    for (int isub = 0; isub < 8; ++isub) {
      const float* wp = weight + (size_t)(ic * 8 + isub) * W_IST
                               + (size_t)o0 * W_OST + loc * 9;
      #pragma unroll
      for (int kk = 0; kk < 9; ++kk) {
        float a = As[(kk * 8 + isub) * 64 + b];
        #pragma unroll
        for (int j = 0; j < 16; ++j)
          acc[j] = fmaf(a, wp[(size_t)j * W_OST + kk], acc[j]);
      }
    }
  }
  size_t ob = ((size_t)b * 64 + o0) * NLOC + loc;
  #pragma unroll
  for (int j = 0; j < 16; ++j) out[ob + (size_t)j * NLOC] = acc[j];
}

// ---------------------------------------------------------------------------
extern "C" void kernel_launch(void* const* d_in, const int* in_sizes, int n_in,
                              void* d_out, int out_size, void* d_ws, size_t ws_size,
                              hipStream_t stream) {
  const float* x  = (const float*)d_in[0];
  const float* wt = (const float*)d_in[1];
  const float* bs = (const float*)d_in[2];
  float* out = (float*)d_out;

  if (ws_size >= WS_NEED) {
    unsigned short* xtb = (unsigned short*)d_ws;
    unsigned short* wt2 = (unsigned short*)((char*)d_ws + XT_BYTES);
    xpose_pad<<<64 * HP_, 256, 0, stream>>>(x, xtb);
    wtrans<<<4 * 512, 256, 0, stream>>>(wt, wt2);
    lc2d_mfma_pre<<<NLOC, 256, 0, stream>>>(xtb, wt2, bs, out);
  } else if (ws_size >= XT_BYTES) {
    unsigned short* xtb = (unsigned short*)d_ws;
    xpose_pad<<<64 * HP_, 256, 0, stream>>>(x, xtb);
    lc2d_mfma_gather<<<NLOC, 256, 0, stream>>>(xtb, wt, bs, out);
  } else {
    lc2d_fallback<<<NLOC, 256, 0, stream>>>(x, wt, bs, out);
  }
}